// Round 9
// baseline (9378.979 us; speedup 1.0000x reference)
//
#include <hip/hip_runtime.h>

#define BSZ 32
#define T 1024
#define D 512
#define H 512

// ---------------------------------------------------------------------------
// Round-8 design: accept the measured allocator behavior (always targets
// 2 WGs/CU -> 128 VGPRs for 512-thr WGs; attributes ignored, rounds 2/3/4/7).
// One batch = TWO workgroups (64 WGs, 64 CUs). WG (b,w) owns output rows
// [w*256, w*256+256). Thread j: rows r0=w*256+2*(j>>2), r0+1; col slice
// [(j&3)*128, +128). Weights: 32 uint4/thread = 23 reg (92 VGPR, fits the
// 128 cap with ~34 working) + 9 LDS (73.7 KB).
// Halves exchange h via global scratch (dead w_ih buffer): parity-double-
// buffered 512B slots + monotonic release-counters (device scope).
// h in LDS with +4-u32 pad per 64-u32 slice so the 4 col-slices hit
// distinct banks (round-7's 5e7 conflicts: 256B-apart addrs = same bank).
// ---------------------------------------------------------------------------

typedef _Float16 h2v __attribute__((ext_vector_type(2)));
typedef unsigned long long u64;
union U32H2 { unsigned int u; h2v h; };

__device__ __forceinline__ unsigned int pack2(float x, float y) {
  U32H2 c; c.h = h2v{(_Float16)x, (_Float16)y}; return c.u;
}
__device__ __forceinline__ h2v uph(unsigned int u) { U32H2 c; c.u = u; return c.h; }

#if defined(__has_builtin)
#if __has_builtin(__builtin_amdgcn_fdot2)
#define HAVE_FDOT2 1
#endif
#endif

__device__ __forceinline__ float fdot2f(unsigned int w, unsigned int h, float acc) {
#ifdef HAVE_FDOT2
  return __builtin_amdgcn_fdot2(uph(w), uph(h), acc, false);
#else
  h2v wv = uph(w), hv = uph(h);
  acc = fmaf((float)wv[0], (float)hv[0], acc);
  return fmaf((float)wv[1], (float)hv[1], acc);
#endif
}

// Load 8 consecutive f32 weights -> uint4 of 4 packed f16 pairs.
__device__ __forceinline__ uint4 ldw(const float* p) {
  const float4 a = *(const float4*)p;
  const float4 b = *(const float4*)(p + 4);
  uint4 r;
  r.x = pack2(a.x, a.y); r.y = pack2(a.z, a.w);
  r.z = pack2(b.x, b.y); r.w = pack2(b.z, b.w);
  return r;
}

// ---------------------------------------------------------------------------
// Projection GEMM: C[m][n] = sum_d A[m][d] * W[n][d]   (fp32, 64x64 tile)
// ---------------------------------------------------------------------------
#define BM 64
#define BN 64
#define BK 32

__global__ __launch_bounds__(256) void gemm_proj(const float* __restrict__ A,
                                                 const float* __restrict__ W,
                                                 float* __restrict__ C) {
  __shared__ float As[BK][BM + 4];
  __shared__ float Bs[BK][BN + 4];
  const int bn = blockIdx.x * BN;
  const int bm = blockIdx.y * BM;
  const int tid = threadIdx.x;
  const int tx = tid & 15;
  const int ty = tid >> 4;
  float acc[4][4] = {};

  for (int k0 = 0; k0 < D; k0 += BK) {
    const int c = tid & 31;
    const int r0 = tid >> 5;
    #pragma unroll
    for (int i = 0; i < 8; ++i) {
      const int r = r0 + i * 8;
      As[c][r] = A[(size_t)(bm + r) * D + (k0 + c)];
      Bs[c][r] = W[(size_t)(bn + r) * D + (k0 + c)];
    }
    __syncthreads();
    #pragma unroll
    for (int kk = 0; kk < BK; ++kk) {
      const float4 av = *(const float4*)&As[kk][ty * 4];
      const float4 bv = *(const float4*)&Bs[kk][tx * 4];
      acc[0][0] = fmaf(av.x, bv.x, acc[0][0]);
      acc[0][1] = fmaf(av.x, bv.y, acc[0][1]);
      acc[0][2] = fmaf(av.x, bv.z, acc[0][2]);
      acc[0][3] = fmaf(av.x, bv.w, acc[0][3]);
      acc[1][0] = fmaf(av.y, bv.x, acc[1][0]);
      acc[1][1] = fmaf(av.y, bv.y, acc[1][1]);
      acc[1][2] = fmaf(av.y, bv.z, acc[1][2]);
      acc[1][3] = fmaf(av.y, bv.w, acc[1][3]);
      acc[2][0] = fmaf(av.z, bv.x, acc[2][0]);
      acc[2][1] = fmaf(av.z, bv.y, acc[2][1]);
      acc[2][2] = fmaf(av.z, bv.z, acc[2][2]);
      acc[2][3] = fmaf(av.z, bv.w, acc[2][3]);
      acc[3][0] = fmaf(av.w, bv.x, acc[3][0]);
      acc[3][1] = fmaf(av.w, bv.y, acc[3][1]);
      acc[3][2] = fmaf(av.w, bv.z, acc[3][2]);
      acc[3][3] = fmaf(av.w, bv.w, acc[3][3]);
    }
    __syncthreads();
  }
  #pragma unroll
  for (int i = 0; i < 4; ++i) {
    float4 o;
    o.x = acc[i][0]; o.y = acc[i][1]; o.z = acc[i][2]; o.w = acc[i][3];
    *(float4*)&C[(size_t)(bm + ty * 4 + i) * H + (bn + tx * 4)] = o;
  }
}

// ---- weight-register macros (literal element access only) ------------------
#define DECLR(P, wr) \
  uint4 P##0 = ldw((wr) + 0),  P##1 = ldw((wr) + 8),  P##2 = ldw((wr) + 16), \
        P##3 = ldw((wr) + 24), P##4 = ldw((wr) + 32), P##5 = ldw((wr) + 40), \
        P##6 = ldw((wr) + 48), P##7 = ldw((wr) + 56), P##8 = ldw((wr) + 64), \
        P##9 = ldw((wr) + 72), P##10 = ldw((wr) + 80), P##11 = ldw((wr) + 88);

// 8 dot2 for one h-quad (2 rows x 4 pairs), 4 accumulator chains.
#define DOT8(wa, wb, idx) { const uint4 hq = *(const uint4*)(hcur + 4 * (idx)); \
  a00 = fdot2f((wa).x, hq.x, a00); a10 = fdot2f((wb).x, hq.x, a10); \
  a01 = fdot2f((wa).y, hq.y, a01); a11 = fdot2f((wb).y, hq.y, a11); \
  a00 = fdot2f((wa).z, hq.z, a00); a10 = fdot2f((wb).z, hq.z, a10); \
  a01 = fdot2f((wa).w, hq.w, a01); a11 = fdot2f((wb).w, hq.w, a11); }

// ---------------------------------------------------------------------------
// Recurrence: 2 WGs per batch; h halves exchanged via global scratch.
// ---------------------------------------------------------------------------
__global__ __attribute__((amdgpu_flat_work_group_size(512, 512)))
void rnn_rec(const float* __restrict__ Z,
             const float* __restrict__ Whh,
             const float* __restrict__ b_ih,
             const float* __restrict__ b_hh,
             float* __restrict__ Y,
             float* __restrict__ Hlast,
             unsigned int* aux) {
  const int bid = blockIdx.x;
  const int b = bid >> 1, w = bid & 1;
  const int j = threadIdx.x;
  const int s = j & 3;          // column slice: cols [s*128, s*128+128)
  const int rg = j >> 2;        // row group: rows r0, r0+1
  const int r0 = w * 256 + 2 * rg;

  // h(t) as f16 pairs: hbp[parity][slice][64 data + 4 pad] -> slices on
  // distinct banks (68*4B = 272B = 17 banks apart).
  __shared__ __align__(16) unsigned int hbp[2][4][68];
  __shared__ uint4 wl[9][512];  // LDS weight tail: 73.7 KB

  const float* wr0 = Whh + (size_t)r0 * H + s * 128;
  const float* wr1 = wr0 + H;

  DECLR(A, wr0)                      // row0 groups 0..11 in regs
  uint4 B0 = ldw(wr1 + 0),  B1 = ldw(wr1 + 8),  B2 = ldw(wr1 + 16),
        B3 = ldw(wr1 + 24), B4 = ldw(wr1 + 32), B5 = ldw(wr1 + 40),
        B6 = ldw(wr1 + 48), B7 = ldw(wr1 + 56), B8 = ldw(wr1 + 64),
        B9 = ldw(wr1 + 72), B10 = ldw(wr1 + 80);   // row1 groups 0..10

  // LDS tail: wl[0..3] = row0 groups 12..15; wl[4..8] = row1 groups 11..15.
  #pragma unroll
  for (int q = 0; q < 4; ++q) wl[q][j] = ldw(wr0 + 8 * (12 + q));
  #pragma unroll
  for (int q = 0; q < 5; ++q) wl[4 + q][j] = ldw(wr1 + 8 * (11 + q));

  float bias0 = 0.f, bias1 = 0.f, h0 = 0.f, h1 = 0.f;
  if (s == 0) {
    bias0 = b_ih[r0] + b_hh[r0];
    bias1 = b_ih[r0 + 1] + b_hh[r0 + 1];
  }
  if (j < 272) ((unsigned int*)hbp)[j] = 0u;   // h(0) = 0 (both halves)
  __syncthreads();

  unsigned int* cnt = aux;                      // [64] step counters
  unsigned int* Hx  = aux + 1024;               // [32][2][2][128] h halves
  unsigned int* myCnt = &cnt[b * 2 + w];
  unsigned int* otCnt = &cnt[b * 2 + (1 - w)];

  const float* zb = Z + (size_t)b * T * H;
  float* yb = Y + (size_t)b * T * H;

  #pragma unroll 1
  for (int t = 0; t < T; ++t) {
    const int par = t & 1, nxt = par ^ 1;
    // --- Phase A: stage remote half of h(t) into LDS; issue z load ---------
    if (t && j < 64) {
      const unsigned int tgt = 32u * (unsigned int)t;
      while (__hip_atomic_load(otCnt, __ATOMIC_ACQUIRE,
                               __HIP_MEMORY_SCOPE_AGENT) < tgt)
        __builtin_amdgcn_s_sleep(2);
      unsigned int* src = Hx + (((size_t)b * 2 + par) * 2 + (1 - w)) * 128;
      u64 v = __hip_atomic_load((u64*)(src + 2 * j), __ATOMIC_RELAXED,
                                __HIP_MEMORY_SCOPE_AGENT);
      const int sg = 2 * (1 - w) + (j >> 5);
      *(u64*)&hbp[par][sg][(2 * j) & 63] = v;
    }
    float2 zv = make_float2(0.f, 0.f);
    if (s == 0) zv = *(const float2*)&zb[(size_t)t * H + r0];
    __syncthreads();
    // --- Phase C: full 512-col dot for 2 rows ------------------------------
    const unsigned int* hcur = &hbp[par][s][0];
    float a00 = 0.f, a01 = 0.f, a10 = 0.f, a11 = 0.f;
    DOT8(A0, B0, 0)  DOT8(A1, B1, 1)  DOT8(A2, B2, 2)  DOT8(A3, B3, 3)
    DOT8(A4, B4, 4)  DOT8(A5, B5, 5)  DOT8(A6, B6, 6)  DOT8(A7, B7, 7)
    DOT8(A8, B8, 8)  DOT8(A9, B9, 9)  DOT8(A10, B10, 10)
    { const uint4 wb = wl[4][j]; DOT8(A11, wb, 11) }
    #pragma unroll
    for (int q = 0; q < 4; ++q) {
      const uint4 wa = wl[q][j];
      const uint4 wb = wl[5 + q][j];
      DOT8(wa, wb, 12 + q)
    }
    float r0s = a00 + a01, r1s = a10 + a11;
    r0s += __shfl_xor(r0s, 1); r0s += __shfl_xor(r0s, 2);
    r1s += __shfl_xor(r1s, 1); r1s += __shfl_xor(r1s, 2);
    if (s == 0) {
      const float p0 = zv.x + bias0 + r0s;
      const float p1 = zv.y + bias1 + r1s;
      const float e0 = __expf(2.f * p0), e1 = __expf(2.f * p1);
      h0 = 1.f - 2.f / (e0 + 1.f);
      h1 = 1.f - 2.f / (e1 + 1.f);
      hbp[nxt][2 * w + (rg >> 6)][rg & 63] = pack2(h0, h1);
      *(float2*)&yb[(size_t)t * H + r0] = make_float2(h0, h1);
    }
    __syncthreads();
    // --- Phase F: post own half of h(t+1) + release counter ---------------
    if (j < 32) {
      const int sg = 2 * w + ((4 * j) >> 6);
      const int ix = (4 * j) & 63;
      const u64 v0 = *(const u64*)&hbp[nxt][sg][ix];
      const u64 v1 = *(const u64*)&hbp[nxt][sg][ix + 2];
      unsigned int* dst = Hx + (((size_t)b * 2 + nxt) * 2 + w) * 128 + 4 * j;
      __hip_atomic_store((u64*)dst, v0, __ATOMIC_RELEASE,
                         __HIP_MEMORY_SCOPE_AGENT);
      __hip_atomic_store((u64*)(dst + 2), v1, __ATOMIC_RELEASE,
                         __HIP_MEMORY_SCOPE_AGENT);
      __hip_atomic_fetch_add(myCnt, 1u, __ATOMIC_RELEASE,
                             __HIP_MEMORY_SCOPE_AGENT);
    }
  }
  if (s == 0) {
    Hlast[(size_t)b * H + r0]     = h0;
    Hlast[(size_t)b * H + r0 + 1] = h1;
  }
}

// ---------------------------------------------------------------------------
extern "C" void kernel_launch(void* const* d_in, const int* in_sizes, int n_in,
                              void* d_out, int out_size, void* d_ws, size_t ws_size,
                              hipStream_t stream) {
  const float* x     = (const float*)d_in[0];
  const float* w_ih0 = (const float*)d_in[1];
  const float* w_hh0 = (const float*)d_in[2];
  const float* b_ih0 = (const float*)d_in[3];
  const float* b_hh0 = (const float*)d_in[4];
  const float* w_ih1 = (const float*)d_in[5];
  const float* w_hh1 = (const float*)d_in[6];
  const float* b_ih1 = (const float*)d_in[7];
  const float* b_hh1 = (const float*)d_in[8];

  float* out = (float*)d_out;
  float* Y  = out;                                  // y1 region [B*T*H]
  float* HL = out + (size_t)BSZ * T * H;            // hidden [2][B][H]
  float* Z  = (float*)d_ws;                         // pre-activations [B*T*H]

  // Exchange scratch lives in the (dead-after-projection) w_ih buffers:
  // [0..63] u32 counters, [1024..17407] u32 h-half slots. 70 KB of 1 MB.
  unsigned int* aux0 = (unsigned int*)w_ih0;
  unsigned int* aux1 = (unsigned int*)w_ih1;

  const dim3 ggrid(H / BN, (BSZ * T) / BM);         // (8, 512)

  gemm_proj<<<ggrid, 256, 0, stream>>>(x, w_ih0, Z);
  hipMemsetAsync(aux0, 0, 64 * sizeof(unsigned int), stream);
  rnn_rec<<<BSZ * 2, 512, 0, stream>>>(Z, w_hh0, b_ih0, b_hh0, Y, HL, aux0);

  gemm_proj<<<ggrid, 256, 0, stream>>>(Y, w_ih1, Z);
  hipMemsetAsync(aux1, 0, 64 * sizeof(unsigned int), stream);
  rnn_rec<<<BSZ * 2, 512, 0, stream>>>(Z, w_hh1, b_ih1, b_hh1, Y,
                                       HL + (size_t)BSZ * H, aux1);
}